// Round 11
// baseline (1105.149 us; speedup 1.0000x reference)
//
#include <hip/hip_runtime.h>
#include <math.h>

// GNN_node_Virtualnode: B=128 graphs, 256 nodes/graph, 2048 edges/graph,
// emb=256, 5 GIN layers + virtual node, learned dense-adjacency propagation.
// Round 11: k_agg v2 (16 nodes/block, bf16 ee table, 1-deep edge software
// pipeline, XCD swizzle); k_bnsplit deleted — BN1+relu folded into GEMM2's
// reg-staged A-operand (B stays global_load_lds).

#define B_G   128
#define NPG   256
#define EPG   2048
#define EMB   256
#define NL    5
#define NNODE (B_G*NPG)   // 32768
#define NEDGE (B_G*EPG)   // 262144
#define FBUF  8388608     // floats per 33.55MB buffer

typedef __attribute__((ext_vector_type(8))) short bf16x8;
typedef __attribute__((ext_vector_type(4))) float f32x4;

// ---------------- helpers ----------------
__device__ __forceinline__ unsigned short round1(float x) {
  // round-to-nearest-even bf16
  unsigned u = __builtin_bit_cast(unsigned, x);
  return (unsigned short)((u + 0x7FFFu + ((u >> 16) & 1u)) >> 16);
}

__device__ __forceinline__ float bdec(unsigned short h) {
  return __builtin_bit_cast(float, (unsigned)h << 16);
}

__device__ __forceinline__ void gload16(unsigned short* lds, const unsigned short* g) {
  // async global->LDS, 16B/lane; LDS dest = wave-uniform base + lane*16
  __builtin_amdgcn_global_load_lds(
      (const __attribute__((address_space(1))) unsigned int*)g,
      (__attribute__((address_space(3))) unsigned int*)lds, 16, 0, 0);
}

__global__ void k_zero(uint4* p, int n16) {
  int i = blockIdx.x * 256 + threadIdx.x;
  if (i < n16) p[i] = make_uint4(0, 0, 0, 0);
}

// 16-entry sigmoid edge-weight table: 16 waves, one per bond value
__global__ void k_ewtbl(const float* __restrict__ bh, const float* __restrict__ w,
                        const float* __restrict__ b, float* __restrict__ tbl) {
  int v = threadIdx.x >> 6, t = threadIdx.x & 63;
  float p = bh[v * 64 + t] * w[t];
  for (int off = 32; off; off >>= 1) p += __shfl_down(p, off, 64);
  if (t == 0) tbl[v] = 1.0f / (1.0f + expf(-(p + b[0])));
}

// Deterministic duplicate resolution: last edge (max e) wins.
__global__ void k_pack_adj(const int* __restrict__ lei, const int* __restrict__ ea,
                           int* __restrict__ packed) {
  int idx = blockIdx.x * 256 + threadIdx.x;       // NEDGE
  int g = idx >> 11, e = idx & 2047;
  int s = lei[g * 4096 + e];
  int d = lei[g * 4096 + 2048 + e];
  int v = ((e + 1) << 4) | ea[g * 2048 + e];
  atomicMax(&packed[g * 65536 + s * 256 + d], v);
}

// unpack + eye folded; writes EVERY element (no pre-zero of adj needed)
__global__ void k_unpack_adj(const int* __restrict__ packed,
                             const float* __restrict__ tbl, float* __restrict__ adj) {
  int idx = blockIdx.x * 256 + threadIdx.x;       // 8388608
  int v = packed[idx];
  int r = (idx >> 8) & 255, c = idx & 255;
  adj[idx] = (v ? tbl[v & 15] : 0.0f) + (r == c ? 1.0f : 0.0f);
}

// per-graph colsum^-1/2 and rowsum^-1/2 (sums only; scaling fused into k_ascale)
__global__ __launch_bounds__(256)
void k_degsums(const float* __restrict__ adj, float* __restrict__ CSv,
               float* __restrict__ RCv) {
  int g = blockIdx.x, t = threadIdx.x;
  const float* Ag = adj + (size_t)g * 65536;
  float s0 = 0, s1 = 0, s2 = 0, s3 = 0;
  for (int i = 0; i < 256; i += 4) {              // colsum(t), coalesced
    s0 += Ag[(i + 0) * 256 + t]; s1 += Ag[(i + 1) * 256 + t];
    s2 += Ag[(i + 2) * 256 + t]; s3 += Ag[(i + 3) * 256 + t];
  }
  CSv[g * 256 + t] = rsqrtf((s0 + s1) + (s2 + s3));
  float4 r0 = make_float4(0, 0, 0, 0), r1 = r0, r2 = r0, r3 = r0;
  const float4* A4 = (const float4*)(Ag + t * 256);
  for (int j = 0; j < 64; j += 4) {               // rowsum(t)
    float4 v0 = A4[j], v1 = A4[j + 1], v2 = A4[j + 2], v3 = A4[j + 3];
    r0.x += v0.x + v0.y; r0.y += v0.z + v0.w;
    r1.x += v1.x + v1.y; r1.y += v1.z + v1.w;
    r2.x += v2.x + v2.y; r2.y += v2.z + v2.w;
    r3.x += v3.x + v3.y; r3.y += v3.z + v3.w;
  }
  RCv[g * 256 + t] = rsqrtf((r0.x + r0.y) + (r1.x + r1.y) + (r2.x + r2.y) + (r3.x + r3.y));
}

// Ahb[g][i][j] = bf16( cs[i] * adj[i][j] * rc[j] )
__global__ void k_ascale(const float* __restrict__ adj, const float* __restrict__ CSv,
                         const float* __restrict__ RCv, unsigned short* __restrict__ Ahb) {
  int flat = blockIdx.x * 256 + threadIdx.x;      // 2097152 quads
  int g = flat >> 14;
  int i = (flat >> 6) & 255, j4 = (flat & 63) * 4;
  size_t base = (size_t)g * 65536 + i * 256 + j4;
  float4 a = *(const float4*)&adj[base];
  float cs = CSv[g * 256 + i];
  float4 rc = *(const float4*)&RCv[g * 256 + j4];
  ushort4 o;
  o.x = round1(cs * a.x * rc.x); o.y = round1(cs * a.y * rc.y);
  o.z = round1(cs * a.z * rc.z); o.w = round1(cs * a.w * rc.w);
  *(ushort4*)&Ahb[base] = o;
}

// transposed bf16 fea gather: X0h[g][e][n] = bf16(atom_emb[aidx[g*256+n]][e])
__global__ void k_feaTb(const int* __restrict__ aidx, const float* __restrict__ aemb,
                        unsigned short* __restrict__ X0h) {
  int flat = blockIdx.x * 256 + threadIdx.x;      // 2097152 quads
  int base = flat * 4;
  int g = base >> 16, e = (base >> 8) & 255, n0 = base & 255;
  const int* ai = &aidx[g * 256 + n0];
  ushort4 o;
  o.x = round1(aemb[ai[0] * 256 + e]);
  o.y = round1(aemb[ai[1] * 256 + e]);
  o.z = round1(aemb[ai[2] * 256 + e]);
  o.w = round1(aemb[ai[3] * 256 + e]);
  *(ushort4*)&X0h[base] = o;
}

// fused Y-sum + transpose: H0b[z][n][k] = bf16(0.25*(X0+X1+X2+X3)[z][k][n])
__global__ __launch_bounds__(256)
void k_sumT(const unsigned short* __restrict__ X0, const unsigned short* __restrict__ X1,
            const unsigned short* __restrict__ X2, const unsigned short* __restrict__ X3,
            unsigned short* __restrict__ dst) {
  __shared__ float tl[64][65];
  size_t zo = (size_t)blockIdx.z * 65536;
  int n0 = blockIdx.x * 64, k0 = blockIdx.y * 64;
  int t = threadIdx.x;
  int c = (t & 15) * 4, r = t >> 4;
#pragma unroll
  for (int p = 0; p < 4; p++) {
    int rr = r + p * 16;
    size_t off = zo + (size_t)(k0 + rr) * 256 + n0 + c;
    ushort4 a = *(const ushort4*)&X0[off];
    ushort4 b = *(const ushort4*)&X1[off];
    ushort4 cc = *(const ushort4*)&X2[off];
    ushort4 d = *(const ushort4*)&X3[off];
    tl[rr][c + 0] = bdec(a.x) + bdec(b.x) + bdec(cc.x) + bdec(d.x);
    tl[rr][c + 1] = bdec(a.y) + bdec(b.y) + bdec(cc.y) + bdec(d.y);
    tl[rr][c + 2] = bdec(a.z) + bdec(b.z) + bdec(cc.z) + bdec(d.z);
    tl[rr][c + 3] = bdec(a.w) + bdec(b.w) + bdec(cc.w) + bdec(d.w);
  }
  __syncthreads();
#pragma unroll
  for (int p = 0; p < 4; p++) {
    int rr = r + p * 16;
    ushort4 o;
    o.x = round1(tl[c][rr] * 0.25f);     o.y = round1(tl[c + 1][rr] * 0.25f);
    o.z = round1(tl[c + 2][rr] * 0.25f); o.w = round1(tl[c + 3][rr] * 0.25f);
    *(ushort4*)&dst[zo + (size_t)(n0 + rr) * 256 + k0 + c] = o;
  }
}

// weight transpose + bf16 round: dh[z][N][K] = bf16(src[z][K][N])
__global__ __launch_bounds__(256)
void k_wtb(const float* __restrict__ src, unsigned short* __restrict__ dh,
           int K, int N, long ss, long sd) {
  __shared__ float tl[64][65];
  src += (size_t)blockIdx.z * ss;
  dh += (size_t)blockIdx.z * sd;
  int n0 = blockIdx.x * 64, k0 = blockIdx.y * 64;
  int t = threadIdx.x;
  int c = (t & 15) * 4, r = t >> 4;
#pragma unroll
  for (int p = 0; p < 4; p++) {
    int rr = r + p * 16;
    float4 v = *(const float4*)&src[(size_t)(k0 + rr) * N + n0 + c];
    tl[rr][c] = v.x; tl[rr][c + 1] = v.y; tl[rr][c + 2] = v.z; tl[rr][c + 3] = v.w;
  }
  __syncthreads();
#pragma unroll
  for (int p = 0; p < 4; p++) {
    int rr = r + p * 16;
    ushort4 hh;
    hh.x = round1(tl[c][rr]);     hh.y = round1(tl[c + 1][rr]);
    hh.z = round1(tl[c + 2][rr]); hh.w = round1(tl[c + 3][rr]);
    *(ushort4*)&dh[(size_t)(n0 + rr) * K + k0 + c] = hh;
  }
}

// ---- bf16 GEMM (batched): C[z] = op(A[z]) @ B[z]^T + bias; bf16 operands.
// B via global_load_lds; A via gload (ascale==null) or reg-staged with
// BN+relu fold (ascale!=null): a = relu(a*ascale[k]+ashift[k]).
// Optional fused column sum/sumsq. Output: fp32 Cf and/or bf16 Ch.
__global__ __launch_bounds__(256, 4)
void k_bgemm(const unsigned short* __restrict__ A_g, const unsigned short* __restrict__ B_g,
             const float* __restrict__ bias, float* __restrict__ Cf,
             unsigned short* __restrict__ Ch,
             float* __restrict__ Ssum, float* __restrict__ Ssq, int K, int N,
             long zA, long zB, long zC,
             const float* __restrict__ ascale, const float* __restrict__ ashift) {
  __shared__ alignas(16) unsigned short As[128 * 64];
  __shared__ alignas(16) unsigned short Bs[128 * 64];
  int z = blockIdx.z;
  A_g += (size_t)z * zA; B_g += (size_t)z * zB;
  if (Cf) Cf += (size_t)z * zC;
  if (Ch) Ch += (size_t)z * zC;
  int rowbase = blockIdx.y * 128, colbase = blockIdx.x * 128;
  int t = threadIdx.x, l = t & 63, wid = t >> 6;
  int wr = wid >> 1, wc = wid & 1;
  int r8 = l >> 3, cb = (l & 7) * 8;               // staging lane -> (row, col)
  f32x4 acc[4][4];
#pragma unroll
  for (int i = 0; i < 4; i++)
#pragma unroll
    for (int j = 0; j < 4; j++) acc[i][j] = (f32x4){0, 0, 0, 0};

  for (int k0 = 0; k0 < K; k0 += 64) {
    __syncthreads();                               // prior readers done
    if (ascale) {
      float4 s0 = *(const float4*)&ascale[k0 + cb];
      float4 s1 = *(const float4*)&ascale[k0 + cb + 4];
      float4 h0 = *(const float4*)&ashift[k0 + cb];
      float4 h1 = *(const float4*)&ashift[k0 + cb + 4];
#pragma unroll
      for (int i = 0; i < 4; i++) {
        int chunk = wid * 4 + i;
        int row = chunk * 8 + r8;
        const unsigned short* src = A_g + (size_t)(rowbase + row) * K + k0 + cb;
        ushort4 v0 = *(const ushort4*)src;
        ushort4 v1 = *(const ushort4*)(src + 4);
        float x;
        ushort4 o0, o1;
#define BNF(dst, u, s, h) x = fmaf(bdec(u), s, h); x = x > 0 ? x : 0; dst = round1(x);
        BNF(o0.x, v0.x, s0.x, h0.x) BNF(o0.y, v0.y, s0.y, h0.y)
        BNF(o0.z, v0.z, s0.z, h0.z) BNF(o0.w, v0.w, s0.w, h0.w)
        BNF(o1.x, v1.x, s1.x, h1.x) BNF(o1.y, v1.y, s1.y, h1.y)
        BNF(o1.z, v1.z, s1.z, h1.z) BNF(o1.w, v1.w, s1.w, h1.w)
#undef BNF
        *(ushort4*)&As[chunk * 512 + l * 8] = o0;
        *(ushort4*)&As[chunk * 512 + l * 8 + 4] = o1;
        gload16(Bs + chunk * 512, B_g + (size_t)(colbase + row) * K + k0 + cb);
      }
    } else {
#pragma unroll
      for (int i = 0; i < 4; i++) {
        int chunk = wid * 4 + i;                   // 0..15 -> 8 rows each
        int row = chunk * 8 + r8;
        gload16(As + chunk * 512, A_g + (size_t)(rowbase + row) * K + k0 + cb);
        gload16(Bs + chunk * 512, B_g + (size_t)(colbase + row) * K + k0 + cb);
      }
    }
    __syncthreads();                               // vmcnt+lgkm drain + barrier
#pragma unroll
    for (int ks = 0; ks < 2; ks++) {
      bf16x8 ah[4], bh[4];
#pragma unroll
      for (int fm = 0; fm < 4; fm++) {
        int r = wr * 64 + fm * 16 + (l & 15);
        ah[fm] = *(const bf16x8*)&As[r * 64 + ks * 32 + (l >> 4) * 8];
      }
#pragma unroll
      for (int fn = 0; fn < 4; fn++) {
        int c = wc * 64 + fn * 16 + (l & 15);
        bh[fn] = *(const bf16x8*)&Bs[c * 64 + ks * 32 + (l >> 4) * 8];
      }
#pragma unroll
      for (int fm = 0; fm < 4; fm++)
#pragma unroll
        for (int fn = 0; fn < 4; fn++)
          acc[fm][fn] = __builtin_amdgcn_mfma_f32_16x16x32_bf16(ah[fm], bh[fn], acc[fm][fn], 0, 0, 0);
    }
  }
  __syncthreads();
  float bi[4], scoll[4] = {0, 0, 0, 0}, qcoll[4] = {0, 0, 0, 0};
#pragma unroll
  for (int fn = 0; fn < 4; fn++)
    bi[fn] = bias ? bias[colbase + wc * 64 + fn * 16 + (l & 15)] : 0.0f;
#pragma unroll
  for (int fm = 0; fm < 4; fm++)
#pragma unroll
    for (int r4 = 0; r4 < 4; r4++) {
      int row = rowbase + wr * 64 + fm * 16 + (l >> 4) * 4 + r4;
#pragma unroll
      for (int fn = 0; fn < 4; fn++) {
        int col = colbase + wc * 64 + fn * 16 + (l & 15);
        float v = acc[fm][fn][r4] + bi[fn];
        size_t idx = (size_t)row * N + col;
        if (Cf) Cf[idx] = v;
        if (Ch) Ch[idx] = round1(v);
        scoll[fn] += v; qcoll[fn] += v * v;
      }
    }
  if (Ssum) {
    float* scr = (float*)As;                       // 256 floats scratch
    scr[t] = 0.0f;
    __syncthreads();
#pragma unroll
    for (int fn = 0; fn < 4; fn++) {
      int cl_ = wc * 64 + fn * 16 + (l & 15);
      atomicAdd(&scr[cl_ * 2], scoll[fn]);
      atomicAdd(&scr[cl_ * 2 + 1], qcoll[fn]);
    }
    __syncthreads();
    if (t < 128) {
      atomicAdd(&Ssum[colbase + t], scr[t * 2]);
      atomicAdd(&Ssq[colbase + t], scr[t * 2 + 1]);
    }
  }
}

// ---- CSR build (edge structure is layer-invariant; built once) ----
__global__ void k_count(const int* __restrict__ lei, int* __restrict__ counts) {
  int idx = blockIdx.x * 256 + threadIdx.x;
  int g = idx >> 11, e = idx & 2047;
  int d = lei[g * 4096 + 2048 + e];
  atomicAdd(&counts[g * 256 + d], 1);
}

__global__ void k_scan(const int* __restrict__ counts, int* __restrict__ rowptr,
                       int* __restrict__ pos) {
  int g = blockIdx.x, t = threadIdx.x;
  __shared__ int sc[256];
  int own = counts[g * 256 + t];
  sc[t] = own;
  __syncthreads();
  for (int off = 1; off < 256; off <<= 1) {
    int v = 0;
    if (t >= off) v = sc[t - off];
    __syncthreads();
    sc[t] += v;
    __syncthreads();
  }
  int val = g * 2048 + sc[t] - own; // exclusive
  rowptr[g * 256 + t] = val;
  pos[g * 256 + t] = val;
  if (g == B_G - 1 && t == 255) rowptr[B_G * 256] = B_G * 2048;
}

__global__ void k_fill(const int* __restrict__ lei, const int* __restrict__ ea,
                       int* __restrict__ pos, int* __restrict__ csr) {
  int idx = blockIdx.x * 256 + threadIdx.x;
  int g = idx >> 11, e = idx & 2047;
  int s = lei[g * 4096 + e];
  int d = lei[g * 4096 + 2048 + e];
  int eav = ea[g * 2048 + e];
  int slot = atomicAdd(&pos[g * 256 + d], 1);
  csr[slot] = s | (eav << 16);
}

// z = (1+eps)*(h+vn) + sum_{e->this} relu(h[src]+vn+eemb[ea]); H bf16, out bf16
// v2: 16 nodes/block (ee amortized), bf16 ee (8KB LDS), 1-deep edge software
// pipeline, XCD swizzle (graph's 16 blocks on one XCD; 2MB H-slice per L2).
__global__ __launch_bounds__(256)
void k_agg(const unsigned short* __restrict__ H,
           const float* __restrict__ hsc, const float* __restrict__ hsh,
           const float* __restrict__ vn, int vns,
           const float* __restrict__ eemb,
           const int* __restrict__ rowptr, const int* __restrict__ csr,
           const float* __restrict__ geps, int l,
           unsigned short* __restrict__ Zh) {
  __shared__ unsigned short ee[16 * 256];          // bf16 table
  for (int i = threadIdx.x; i < 4096; i += 256) ee[i] = round1(eemb[i]);
  __syncthreads();
  int lane = threadIdx.x & 63, w = threadIdx.x >> 6;
  int bid = (blockIdx.x & 7) * 256 + (blockIdx.x >> 3);  // 2048 blocks, bijective
  int g = bid >> 4;                                // 16 blocks per graph
  int d = lane * 4;
  float eps1 = 1.0f + geps[l];
  float4 sc4 = make_float4(0, 0, 0, 0), sh4 = make_float4(0, 0, 0, 0);
  if (hsc) { sc4 = *(const float4*)&hsc[d]; sh4 = *(const float4*)&hsh[d]; }
  float4 vn4 = *(const float4*)&vn[(size_t)g * vns + d];
  int gbase = g << 8;
#pragma unroll 1
  for (int mi = 0; mi < 4; mi++) {
    int m = bid * 16 + w * 4 + mi;
    int rp = rowptr[m], rp1 = rowptr[m + 1];
    ushort4 hsr = *(const ushort4*)&H[(size_t)m * 256 + d];  // self row (overlaps)
    float4 acc = make_float4(0, 0, 0, 0);
    int cw = 0; ushort4 hr = make_ushort4(0, 0, 0, 0);
    if (rp < rp1) {
      cw = csr[rp];
      hr = *(const ushort4*)&H[(size_t)(gbase + (cw & 0xFFFF)) * 256 + d];
    }
    for (int j = rp; j < rp1; j++) {
      int cwn = 0; ushort4 hrn = make_ushort4(0, 0, 0, 0);
      if (j + 1 < rp1) {                           // prefetch next edge
        cwn = csr[j + 1];
        hrn = *(const ushort4*)&H[(size_t)(gbase + (cwn & 0xFFFF)) * 256 + d];
      }
      int eav = cw >> 16;
      float4 h4 = make_float4(bdec(hr.x), bdec(hr.y), bdec(hr.z), bdec(hr.w));
      if (hsc) {
        h4.x = fmaf(h4.x, sc4.x, sh4.x); h4.y = fmaf(h4.y, sc4.y, sh4.y);
        h4.z = fmaf(h4.z, sc4.z, sh4.z); h4.w = fmaf(h4.w, sc4.w, sh4.w);
        h4.x = h4.x > 0 ? h4.x : 0; h4.y = h4.y > 0 ? h4.y : 0;
        h4.z = h4.z > 0 ? h4.z : 0; h4.w = h4.w > 0 ? h4.w : 0;
      }
      const ushort4 er = *(const ushort4*)&ee[eav * 256 + d];
      float mx = h4.x + vn4.x + bdec(er.x); float my = h4.y + vn4.y + bdec(er.y);
      float mz = h4.z + vn4.z + bdec(er.z); float mw = h4.w + vn4.w + bdec(er.w);
      acc.x += mx > 0 ? mx : 0; acc.y += my > 0 ? my : 0;
      acc.z += mz > 0 ? mz : 0; acc.w += mw > 0 ? mw : 0;
      cw = cwn; hr = hrn;
    }
    float4 hs = make_float4(bdec(hsr.x), bdec(hsr.y), bdec(hsr.z), bdec(hsr.w));
    if (hsc) {
      hs.x = fmaf(hs.x, sc4.x, sh4.x); hs.y = fmaf(hs.y, sc4.y, sh4.y);
      hs.z = fmaf(hs.z, sc4.z, sh4.z); hs.w = fmaf(hs.w, sc4.w, sh4.w);
      hs.x = hs.x > 0 ? hs.x : 0; hs.y = hs.y > 0 ? hs.y : 0;
      hs.z = hs.z > 0 ? hs.z : 0; hs.w = hs.w > 0 ? hs.w : 0;
    }
    float4 z4;
    z4.x = eps1 * (hs.x + vn4.x) + acc.x;
    z4.y = eps1 * (hs.y + vn4.y) + acc.y;
    z4.z = eps1 * (hs.z + vn4.z) + acc.z;
    z4.w = eps1 * (hs.w + vn4.w) + acc.w;
    ushort4 hh;
    hh.x = round1(z4.x); hh.y = round1(z4.y);
    hh.z = round1(z4.z); hh.w = round1(z4.w);
    *(ushort4*)&Zh[(size_t)m * 256 + d] = hh;
  }
}

// contention-free partial colsums of transformed h (bf16): VNP[p][g][256]
__global__ __launch_bounds__(256)
void k_vnsum(const unsigned short* __restrict__ H,
             const float* __restrict__ hsc, const float* __restrict__ hsh,
             float* __restrict__ VNP) {
  int g = blockIdx.x >> 1, p = blockIdx.x & 1, t = threadIdx.x;
  float sc = 0, sh = 0;
  if (hsc) { sc = hsc[t]; sh = hsh[t]; }
  int base = g * 256 + p * 128;
  float s0 = 0, s1 = 0, s2 = 0, s3 = 0;           // 4-deep ILP
  for (int i = 0; i < 128; i += 4) {
    float v0 = bdec(H[(size_t)(base + i + 0) * 256 + t]);
    float v1 = bdec(H[(size_t)(base + i + 1) * 256 + t]);
    float v2 = bdec(H[(size_t)(base + i + 2) * 256 + t]);
    float v3 = bdec(H[(size_t)(base + i + 3) * 256 + t]);
    if (hsc) {
      v0 = fmaf(v0, sc, sh); v0 = v0 > 0 ? v0 : 0;
      v1 = fmaf(v1, sc, sh); v1 = v1 > 0 ? v1 : 0;
      v2 = fmaf(v2, sc, sh); v2 = v2 > 0 ? v2 : 0;
      v3 = fmaf(v3, sc, sh); v3 = v3 > 0 ? v3 : 0;
    }
    s0 += v0; s1 += v1; s2 += v2; s3 += v3;
  }
  VNP[(size_t)(p * 128 + g) * 256 + t] = (s0 + s1) + (s2 + s3);
}

// vn_out = relu(relu(vt@W1+B1)@W2+B2), vt = VNP[0][g]+VNP[1][g] + 257*vn
__global__ __launch_bounds__(256)
void k_vn(const float* __restrict__ VNP,
          const float* __restrict__ vn_in, int vns,
          const float* __restrict__ W1, const float* __restrict__ B1,
          const float* __restrict__ W2, const float* __restrict__ B2,
          float* __restrict__ vn_out) {
  int g = blockIdx.x, t = threadIdx.x;
  __shared__ float vt[256];
  __shared__ float u[512];
  vt[t] = VNP[(size_t)g * 256 + t] + VNP[(size_t)(128 + g) * 256 + t]
        + 257.0f * vn_in[(size_t)g * vns + t];
  __syncthreads();
  for (int o = t; o < 512; o += 256) {
    float a = B1[o];
    for (int k = 0; k < 256; k++) a = fmaf(vt[k], W1[k * 512 + o], a);
    u[o] = a > 0 ? a : 0;
  }
  __syncthreads();
  float a = B2[t];
  for (int k = 0; k < 512; k++) a = fmaf(u[k], W2[k * 256 + t], a);
  vn_out[g * 256 + t] = a > 0 ? a : 0;
}

__global__ void k_bnfin(const float* __restrict__ Ssum, const float* __restrict__ Ssq,
                        const float* __restrict__ g, const float* __restrict__ b,
                        float* __restrict__ scale, float* __restrict__ shift,
                        int NC, float invN) {
  int c = blockIdx.x * 256 + threadIdx.x;
  if (c >= NC) return;
  float mu = Ssum[c] * invN;
  float var = Ssq[c] * invN - mu * mu;
  float rs = rsqrtf(var + 1e-5f);
  float s = rs * g[c];
  scale[c] = s;
  shift[c] = b[c] - mu * s;
}

// out = t2*sc[c]+sh[c] (final BN, JK='last', no relu); T2 fp32 (last layer)
__global__ void k_final(const float* __restrict__ T2, const float* __restrict__ sc,
                        const float* __restrict__ sh, float* __restrict__ out) {
  int i = blockIdx.x * 256 + threadIdx.x; // 2097152 float4s
  int c4 = (i & 63) * 4;
  float4 v = *(const float4*)&T2[(size_t)i * 4];
  float4 s4 = *(const float4*)&sc[c4];
  float4 h4 = *(const float4*)&sh[c4];
  v.x = fmaf(v.x, s4.x, h4.x); v.y = fmaf(v.y, s4.y, h4.y);
  v.z = fmaf(v.z, s4.z, h4.z); v.w = fmaf(v.w, s4.w, h4.w);
  *(float4*)&out[(size_t)i * 4] = v;
}

extern "C" void kernel_launch(void* const* d_in, const int* in_sizes, int n_in,
                              void* d_out, int out_size, void* d_ws, size_t ws_size,
                              hipStream_t stream) {
  (void)in_sizes; (void)n_in; (void)out_size; (void)ws_size;
  const int*   atom_idx = (const int*)d_in[0];
  const int*   lei      = (const int*)d_in[1];
  const int*   eattr    = (const int*)d_in[2];
  const float* atom_emb = (const float*)d_in[4];
  const float* bemb_h   = (const float*)d_in[5];
  const float* elw      = (const float*)d_in[6];
  const float* elb      = (const float*)d_in[7];
  const float* bemb_l   = (const float*)d_in[8];
  const float* geps     = (const float*)d_in[9];
  const float* mw1      = (const float*)d_in[10];
  const float* mb1      = (const float*)d_in[11];
  const float* mbng     = (const float*)d_in[12];
  const float* mbnb     = (const float*)d_in[13];
  const float* mw2      = (const float*)d_in[14];
  const float* mb2      = (const float*)d_in[15];
  const float* obng     = (const float*)d_in[16];
  const float* obnb     = (const float*)d_in[17];
  const float* vne      = (const float*)d_in[18];
  const float* vw1      = (const float*)d_in[19];
  const float* vb1      = (const float*)d_in[20];
  const float* vw2      = (const float*)d_in[21];
  const float* vb2      = (const float*)d_in[22];
  float* out = (float*)d_out;

  // ws layout (33.55MB units):
  // U0: adj fp32 -> later T2b bf16 / T2f fp32
  // U1: X0h|X1h bf16 -> later T1h bf16 (full unit)
  // U2: X2h|X3h bf16
  // U3: PACKED int -> later H0b bf16 (lo half)
  // U4: Zh bf16 | Ahb bf16
  float* W   = (float*)d_ws;
  float* A_  = W;
  float* U1  = W + (size_t)FBUF;
  float* U2  = W + (size_t)2 * FBUF;
  float* U3  = W + (size_t)3 * FBUF;
  float* Z_  = W + (size_t)4 * FBUF;
  float* SM  = W + (size_t)5 * FBUF;
  float* EWT = SM;                   // 16
  float* S1S = SM + 256;             // 512
  float* S1Q = SM + 768;             // 512
  float* S2S = SM + 1280;            // 256
  float* S2Q = SM + 1536;            // 256  (S1S..S2Q contiguous 1536)
  float* SC2 = SM + 1792;            // 256
  float* SH2 = SM + 2048;            // 256
  float* SC1 = SM + 2304;            // 512
  float* SH1 = SM + 2816;            // 512
  float* VNA = SM + 3328;            // 32768
  float* VNB = SM + 36096;           // 32768
  float* CSv = SM + 68864;           // 32768
  float* RCv = SM + 101632;          // 32768
  int* ROWPTR = (int*)(SM + 134400); // 32772
  int* POS    = ROWPTR + 32772;      // 32768
  int* COUNTS = POS + 32768;         // 32768
  int* CSR    = COUNTS + 32768;      // 262144
  unsigned short* W1hT = (unsigned short*)(SM + 494852);  // 5*512*256 shorts
  unsigned short* W2hT = (unsigned short*)(SM + 822532);  // 5*256*512 shorts
  float* T2f = A_;                             // fp32, layer-4 output
  unsigned short* T2b = (unsigned short*)A_;   // bf16, layers 0..3 output
  unsigned short* H0b = (unsigned short*)U3;   // bf16 prop output
  int* PACKED = (int*)U3;
  unsigned short* X0h = (unsigned short*)U1;
  unsigned short* X1h = X0h + 8388608;
  unsigned short* X2h = (unsigned short*)U2;
  unsigned short* X3h = X2h + 8388608;
  unsigned short* T1h = (unsigned short*)U1;   // [32768][512] bf16 = full U1
  unsigned short* Zh  = (unsigned short*)Z_;   // [32768][256] bf16, U4 lo half
  unsigned short* Ahb = (unsigned short*)(Z_ + (size_t)FBUF / 2); // U4 hi half
  float* VNP  = (float*)POS;         // [2][128][256]; POS dead after CSR build

  // ---- stage 1: dense learned-adjacency propagation (bf16, transposed) ----
  k_zero<<<8192, 256, 0, stream>>>((uint4*)PACKED, 2097152);
  k_zero<<<32, 256, 0, stream>>>((uint4*)COUNTS, 8192);
  k_ewtbl<<<1, 1024, 0, stream>>>(bemb_h, elw, elb, EWT);
  k_pack_adj<<<NEDGE / 256, 256, 0, stream>>>(lei, eattr, PACKED);
  k_unpack_adj<<<32768, 256, 0, stream>>>(PACKED, EWT, A_);   // + eye
  k_degsums<<<B_G, 256, 0, stream>>>(A_, CSv, RCv);
  k_ascale<<<8192, 256, 0, stream>>>(A_, CSv, RCv, Ahb);
  // weight transpose + bf16 round (once)
  k_wtb<<<dim3(8, 4, 5), 256, 0, stream>>>(mw1, W1hT, 256, 512, 131072, 131072);
  k_wtb<<<dim3(4, 8, 5), 256, 0, stream>>>(mw2, W2hT, 512, 256, 131072, 131072);
  k_feaTb<<<8192, 256, 0, stream>>>(atom_idx, atom_emb, X0h);
  // order=3: Xt_{i+1} = Xt_i @ A^T (batched bf16 MFMA GEMM, no Y RMW)
  k_bgemm<<<dim3(2, 2, B_G), 256, 0, stream>>>(X0h, Ahb, nullptr, nullptr, X1h,
      nullptr, nullptr, 256, 256, 65536, 65536, 65536, nullptr, nullptr);
  k_bgemm<<<dim3(2, 2, B_G), 256, 0, stream>>>(X1h, Ahb, nullptr, nullptr, X2h,
      nullptr, nullptr, 256, 256, 65536, 65536, 65536, nullptr, nullptr);
  k_bgemm<<<dim3(2, 2, B_G), 256, 0, stream>>>(X2h, Ahb, nullptr, nullptr, X3h,
      nullptr, nullptr, 256, 256, 65536, 65536, 65536, nullptr, nullptr);
  // H0b[n][e] = bf16(0.25*(X0+X1+X2+X3)[e][n])  (PACKED dead; H0b = U3)
  k_sumT<<<dim3(4, 4, B_G), 256, 0, stream>>>(X0h, X1h, X2h, X3h, H0b);

  // ---- CSR (once; edges invariant across layers) ----
  k_count<<<NEDGE / 256, 256, 0, stream>>>(lei, COUNTS);
  k_scan<<<B_G, 256, 0, stream>>>(COUNTS, ROWPTR, POS);
  k_fill<<<NEDGE / 256, 256, 0, stream>>>(lei, eattr, POS, CSR);

  // ---- GIN + virtual-node stack ----
  const float* vn_cur = vne; int vns = 0;   // layer0 vn = vn_emb broadcast
  float* vn_next = VNA;
  for (int l = 0; l < NL; l++) {
    const unsigned short* hsrc = (l == 0) ? H0b : T2b;
    const float* hsc  = (l == 0) ? nullptr : SC2;
    const float* hsh  = (l == 0) ? nullptr : SH2;
    k_agg<<<2048, 256, 0, stream>>>(hsrc, hsc, hsh, vn_cur, vns,
        bemb_l + (size_t)l * 16 * EMB, ROWPTR, CSR, geps, l, Zh);
    if (l < NL - 1) {
      k_vnsum<<<256, 256, 0, stream>>>(hsrc, hsc, hsh, VNP);
      k_vn<<<B_G, 256, 0, stream>>>(VNP, vn_cur, vns,
          vw1 + (size_t)l * EMB * 512, vb1 + (size_t)l * 512,
          vw2 + (size_t)l * 512 * EMB, vb2 + (size_t)l * EMB, vn_next);
    }
    k_zero<<<2, 256, 0, stream>>>((uint4*)S1S, 384);   // S1S,S1Q,S2S,S2Q
    // GEMM1: Zh @ W1^T, raw bf16 T1h + fused stats
    k_bgemm<<<dim3(4, 256, 1), 256, 0, stream>>>(Zh,
        W1hT + (size_t)l * 131072, mb1 + (size_t)l * 512,
        nullptr, T1h, S1S, S1Q, 256, 512, 0, 0, 0, nullptr, nullptr);
    // BN1 finalize -> SC1/SH1 (bnsplit deleted; fold into GEMM2 A-stage)
    k_bnfin<<<2, 256, 0, stream>>>(S1S, S1Q, mbng + (size_t)l * 512,
        mbnb + (size_t)l * 512, SC1, SH1, 512, 1.0f / NNODE);
    // layers 0..3: bf16 T2b (consumed by next layer's gather);
    // layer 4: fp32 T2f (consumed by k_final -> fp32 output path)
    if (l < NL - 1)
      k_bgemm<<<dim3(2, 256, 1), 256, 0, stream>>>(T1h,
          W2hT + (size_t)l * 131072, mb2 + (size_t)l * 256,
          nullptr, T2b, S2S, S2Q, 512, 256, 0, 0, 0, SC1, SH1);
    else
      k_bgemm<<<dim3(2, 256, 1), 256, 0, stream>>>(T1h,
          W2hT + (size_t)l * 131072, mb2 + (size_t)l * 256,
          T2f, nullptr, S2S, S2Q, 512, 256, 0, 0, 0, SC1, SH1);
    k_bnfin<<<1, 256, 0, stream>>>(S2S, S2Q, obng + (size_t)l * EMB,
        obnb + (size_t)l * EMB, SC2, SH2, 256, 1.0f / NNODE);
    if (l < NL - 1) {
      vn_cur = vn_next; vns = EMB;
      vn_next = (vn_next == VNA) ? VNB : VNA;
    }
  }
  k_final<<<8192, 256, 0, stream>>>(T2f, SC2, SH2, out);
}